// Round 7
// baseline (213.842 us; speedup 1.0000x reference)
//
#include <hip/hip_runtime.h>

#define MD   4
#define B_   4
#define C_   128
#define H_   128
#define W_   256
#define ND   9            // 2*MD+1 displacements per axis
#define NW   9            // waves per block, one per dy
#define XPT  4            // x pixels per lane (64 lanes cover W)

typedef float float4v __attribute__((ext_vector_type(4)));

// One wave per (b,y,dy). Halo via neighbor-lane shuffles (no LDS, no
// barriers). Explicit 2-deep channel-pair software pipeline with NAMED
// registers (no arrays -> no scratch; rule: runtime-indexed vectors spill).
__global__ __launch_bounds__(NW * 64, 5)   // VGPR cap 102 -> 2 blocks/CU
void corr_kernel(const float* __restrict__ t1,
                 const float* __restrict__ t2,
                 float* __restrict__ out) {
    const int tid  = threadIdx.x;
    const int lane = tid & 63;
    const int w    = tid >> 6;                 // wave id == dy
    const int bid  = blockIdx.x;               // XCD swizzle (512 = 8*64)
    const int swz  = (bid & 7) * 64 + (bid >> 3);
    const int y    = swz & (H_ - 1);
    const int b    = swz >> 7;
    const int x0   = lane * XPT;               // 0..252
    const int yy   = y + w - MD;               // this wave's shifted t2 row
    const float scale = 1.0f / (float)C_;

    if (yy < 0 || yy >= H_) {                  // zero-pad region: output = 0
        float4v z = {0.f, 0.f, 0.f, 0.f};
        #pragma unroll
        for (int dx = 0; dx < ND; ++dx) {
            const size_t oidx =
                (((size_t)(b * ND * ND) + w * ND + dx) * H_ + y) * W_ + x0;
            *(float4v*)&out[oidx] = z;
        }
        return;
    }

    float acc[ND][XPT];
    #pragma unroll
    for (int dx = 0; dx < ND; ++dx)
        #pragma unroll
        for (int j = 0; j < XPT; ++j) acc[dx][j] = 0.0f;

    const float* p1 = t1 + (((size_t)(b * C_)) * H_ + y ) * W_ + x0;
    const float* p2 = t2 + (((size_t)(b * C_)) * H_ + yy) * W_ + x0;
    const size_t chstr = (size_t)H_ * W_;

    const bool lm = (lane == 0);    // window extends left of x=0  -> pad 0
    const bool rm = (lane == 63);   // window extends right of W-1 -> pad 0

    auto COMP1 = [&](const float4v a, const float4v v) {
        // win[k] = t2 at x = x0 - 4 + k, k = 0..11 (const-indexed after unroll)
        float win[XPT + 2 * MD];
        #pragma unroll
        for (int k = 0; k < 4; ++k) {
            const float up = __shfl_up(v[k], 1);
            const float dn = __shfl_down(v[k], 1);
            win[k]     = lm ? 0.0f : up;
            win[4 + k] = v[k];
            win[8 + k] = rm ? 0.0f : dn;
        }
        #pragma unroll
        for (int dx = 0; dx < ND; ++dx)
            #pragma unroll
            for (int j = 0; j < XPT; ++j)
                acc[dx][j] = fmaf(a[j], win[dx + j], acc[dx][j]);
    };

    // Named pipeline registers: buffer 0 = {A00,V00,A01,V01} (ch c, c+1),
    // buffer 1 = {A10,V10,A11,V11} (ch c+2, c+3). All static accesses.
    float4v A00, V00, A01, V01, A10, V10, A11, V11;

#define LOAD0(c)                                                   \
    A00 = *(const float4v*)(p1 + (size_t)(c)     * chstr);         \
    V00 = *(const float4v*)(p2 + (size_t)(c)     * chstr);         \
    A01 = *(const float4v*)(p1 + (size_t)(c + 1) * chstr);         \
    V01 = *(const float4v*)(p2 + (size_t)(c + 1) * chstr);
#define LOAD1(c)                                                   \
    A10 = *(const float4v*)(p1 + (size_t)(c)     * chstr);         \
    V10 = *(const float4v*)(p2 + (size_t)(c)     * chstr);         \
    A11 = *(const float4v*)(p1 + (size_t)(c + 1) * chstr);         \
    V11 = *(const float4v*)(p2 + (size_t)(c + 1) * chstr);

    LOAD0(0);                                   // prologue: ch 0,1 in flight
    for (int c = 0; c < C_; c += 4) {
        LOAD1(c + 2);                           // prefetch ch c+2,c+3
        COMP1(A00, V00);                        // ch c
        COMP1(A01, V01);                        // ch c+1
        if (c + 4 < C_) { LOAD0(c + 4); }       // prefetch ch c+4,c+5
        COMP1(A10, V10);                        // ch c+2
        COMP1(A11, V11);                        // ch c+3
    }
#undef LOAD0
#undef LOAD1

    #pragma unroll
    for (int dx = 0; dx < ND; ++dx) {
        float4v o;
        #pragma unroll
        for (int j = 0; j < XPT; ++j) o[j] = acc[dx][j] * scale;
        const size_t oidx =
            (((size_t)(b * ND * ND) + w * ND + dx) * H_ + y) * W_ + x0;
        *(float4v*)&out[oidx] = o;
    }
}

extern "C" void kernel_launch(void* const* d_in, const int* in_sizes, int n_in,
                              void* d_out, int out_size, void* d_ws, size_t ws_size,
                              hipStream_t stream) {
    const float* t1 = (const float*)d_in[0];
    const float* t2 = (const float*)d_in[1];
    float* out      = (float*)d_out;
    corr_kernel<<<dim3(B_ * H_), NW * 64, 0, stream>>>(t1, t2, out);
}

// Round 8
// 80.107 us; speedup vs baseline: 2.6694x; 2.6694x over previous
//
#include <hip/hip_runtime.h>

#define MD   4
#define B_   4
#define C_   128
#define H_   128
#define W_   256
#define ND   9            // 2*MD+1 displacements per axis
#define NW   9            // waves per block, one per dy
#define XPT  4            // x pixels per lane (64 lanes cover W)

typedef float float4v __attribute__((ext_vector_type(4)));

// One wave per (b,y,dy). Halo via neighbor-lane shuffles (no LDS/barriers).
// Depth-1 rotating software pipeline: compute channel c from registers
// loaded last iteration while channel c+1's loads are in flight.
// Body kept small (1x 36-FMA block) -- the R6/R7 4x body broke LLVM's
// full unroll and sent acc[] to scratch (VGPR 48, +190MB scratch writes).
__global__ __launch_bounds__(NW * 64, 5)   // VGPR cap 102 -> 2 blocks/CU
void corr_kernel(const float* __restrict__ t1,
                 const float* __restrict__ t2,
                 float* __restrict__ out) {
    const int tid  = threadIdx.x;
    const int lane = tid & 63;
    const int w    = tid >> 6;                 // wave id == dy
    const int bid  = blockIdx.x;               // XCD swizzle (512 = 8*64)
    const int swz  = (bid & 7) * 64 + (bid >> 3);
    const int y    = swz & (H_ - 1);
    const int b    = swz >> 7;
    const int x0   = lane * XPT;               // 0..252
    const int yy   = y + w - MD;               // this wave's shifted t2 row
    const float scale = 1.0f / (float)C_;

    if (yy < 0 || yy >= H_) {                  // zero-pad region: output = 0
        float4v z = {0.f, 0.f, 0.f, 0.f};
        #pragma unroll
        for (int dx = 0; dx < ND; ++dx) {
            const size_t oidx =
                (((size_t)(b * ND * ND) + w * ND + dx) * H_ + y) * W_ + x0;
            *(float4v*)&out[oidx] = z;
        }
        return;
    }

    float acc[ND][XPT];
    #pragma unroll
    for (int dx = 0; dx < ND; ++dx)
        #pragma unroll
        for (int j = 0; j < XPT; ++j) acc[dx][j] = 0.0f;

    const float* p1 = t1 + (((size_t)(b * C_)) * H_ + y ) * W_ + x0;
    const float* p2 = t2 + (((size_t)(b * C_)) * H_ + yy) * W_ + x0;
    const size_t chstr = (size_t)H_ * W_;

    const bool lm = (lane == 0);    // window extends left of x=0  -> pad 0
    const bool rm = (lane == 63);   // window extends right of W-1 -> pad 0

// 8 shuffles + 36 FMAs on one channel's registers (a, v)
#define COMP(a, v)                                                     \
    {                                                                  \
        float win[XPT + 2 * MD];                                       \
        _Pragma("unroll")                                              \
        for (int k = 0; k < 4; ++k) {                                  \
            const float up = __shfl_up((v)[k], 1);                     \
            const float dn = __shfl_down((v)[k], 1);                   \
            win[k]     = lm ? 0.0f : up;                               \
            win[4 + k] = (v)[k];                                       \
            win[8 + k] = rm ? 0.0f : dn;                               \
        }                                                              \
        _Pragma("unroll")                                              \
        for (int dx = 0; dx < ND; ++dx)                                \
            _Pragma("unroll")                                          \
            for (int j = 0; j < XPT; ++j)                              \
                acc[dx][j] = fmaf((a)[j], win[dx + j], acc[dx][j]);    \
    }

    // rotating pipeline registers (all statically addressed)
    float4v a0 = *(const float4v*)(p1);
    float4v v0 = *(const float4v*)(p2);
    float4v a1, v1;

    #pragma unroll 2
    for (int c = 0; c < C_ - 1; ++c) {
        a1 = *(const float4v*)(p1 + (size_t)(c + 1) * chstr);  // prefetch c+1
        v1 = *(const float4v*)(p2 + (size_t)(c + 1) * chstr);
        COMP(a0, v0);                                          // compute c
        a0 = a1; v0 = v1;                                      // rotate
    }
    COMP(a0, v0);                                              // channel 127
#undef COMP

    #pragma unroll
    for (int dx = 0; dx < ND; ++dx) {
        float4v o;
        #pragma unroll
        for (int j = 0; j < XPT; ++j) o[j] = acc[dx][j] * scale;
        const size_t oidx =
            (((size_t)(b * ND * ND) + w * ND + dx) * H_ + y) * W_ + x0;
        *(float4v*)&out[oidx] = o;
    }
}

extern "C" void kernel_launch(void* const* d_in, const int* in_sizes, int n_in,
                              void* d_out, int out_size, void* d_ws, size_t ws_size,
                              hipStream_t stream) {
    const float* t1 = (const float*)d_in[0];
    const float* t2 = (const float*)d_in[1];
    float* out      = (float*)d_out;
    corr_kernel<<<dim3(B_ * H_), NW * 64, 0, stream>>>(t1, t2, out);
}

// Round 9
// 77.970 us; speedup vs baseline: 2.7426x; 1.0274x over previous
//
#include <hip/hip_runtime.h>

#define MD   4
#define B_   4
#define C_   128
#define H_   128
#define W_   256
#define ND   9            // 2*MD+1 displacements per axis
#define NW   9            // waves per block, one per dy
#define XPT  8            // x pixels per lane; 32 lanes cover W, 2 rows/wave

typedef float float4v __attribute__((ext_vector_type(4)));

// One block per (b, y-pair); 9 waves, one per dy. Each wave handles TWO
// image rows: lanes 0-31 -> row y0, lanes 32-63 -> row y0+1. XPT=8 halves
// shuffle (DS-pipe) ops per FMA vs XPT=4 -- DS was the widest pipe (~44us).
// Half-boundary shuffles (lane 31<->32) are always masked by lm/rm since
// those lanes sit at x=W-8 / x=0 where the halo is pad-zero anyway.
// Per-half OOB t2 rows: clamped load + zero output scale (dead-half data
// cannot reach live-half windows).
__global__ __launch_bounds__(NW * 64, 3)   // VGPR cap 170; 1 block/CU
void corr_kernel(const float* __restrict__ t1,
                 const float* __restrict__ t2,
                 float* __restrict__ out) {
    const int tid  = threadIdx.x;
    const int lane = tid & 63;
    const int w    = tid >> 6;                 // wave id == dy
    const int bid  = blockIdx.x;               // 256 blocks = 8 XCD * 32
    const int swz  = (bid & 7) * 32 + (bid >> 3);
    const int yp   = swz & 63;                 // y-pair index 0..63
    const int b    = swz >> 6;                 // 0..3
    const int y0   = yp * 2;
    const int half = lane >> 5;                // 0: row y0, 1: row y0+1
    const int lx   = lane & 31;
    const int x0   = lx * XPT;                 // 0..248
    const int yrow = y0 + half;                // t1/out row
    const int yy   = yrow + w - MD;            // t2 row (may be OOB)
    const bool live = (0 <= yy) && (yy < H_);
    const int  yc  = yy < 0 ? 0 : (yy > H_ - 1 ? H_ - 1 : yy);
    const float sc = live ? (1.0f / (float)C_) : 0.0f;
    const bool lm  = (lx == 0);                // left halo is pad-zero
    const bool rm  = (lx == 31);               // right halo is pad-zero

    float acc[ND][XPT];
    #pragma unroll
    for (int dx = 0; dx < ND; ++dx)
        #pragma unroll
        for (int j = 0; j < XPT; ++j) acc[dx][j] = 0.0f;

    const float* p1 = t1 + (((size_t)(b * C_)) * H_ + yrow) * W_ + x0;
    const float* p2 = t2 + (((size_t)(b * C_)) * H_ + yc  ) * W_ + x0;
    const size_t chstr = (size_t)H_ * W_;

    for (int c = 0; c < C_; ++c) {
        const float4v a0 = *(const float4v*)(p1 + (size_t)c * chstr);
        const float4v a1 = *(const float4v*)(p1 + (size_t)c * chstr + 4);
        const float4v v0 = *(const float4v*)(p2 + (size_t)c * chstr);
        const float4v v1 = *(const float4v*)(p2 + (size_t)c * chstr + 4);

        // win[k] = t2 at x = x0 - 4 + k, k = 0..15
        float win[XPT + 2 * MD];
        #pragma unroll
        for (int k = 0; k < 4; ++k) {
            const float up = __shfl_up(v1[k], 1);    // lane-1's upper half
            const float dn = __shfl_down(v0[k], 1);  // lane+1's lower half
            win[k]      = lm ? 0.0f : up;
            win[4 + k]  = v0[k];
            win[8 + k]  = v1[k];
            win[12 + k] = rm ? 0.0f : dn;
        }

        #pragma unroll
        for (int dx = 0; dx < ND; ++dx)
            #pragma unroll
            for (int j = 0; j < XPT; ++j) {
                const float aj = (j < 4) ? a0[j] : a1[j - 4];
                acc[dx][j] = fmaf(aj, win[dx + j], acc[dx][j]);
            }
    }

    #pragma unroll
    for (int dx = 0; dx < ND; ++dx) {
        float4v o0, o1;
        #pragma unroll
        for (int j = 0; j < 4; ++j) {
            o0[j] = acc[dx][j]     * sc;
            o1[j] = acc[dx][4 + j] * sc;
        }
        const size_t oidx =
            (((size_t)(b * ND * ND) + w * ND + dx) * H_ + yrow) * W_ + x0;
        *(float4v*)&out[oidx]     = o0;
        *(float4v*)&out[oidx + 4] = o1;
    }
}

extern "C" void kernel_launch(void* const* d_in, const int* in_sizes, int n_in,
                              void* d_out, int out_size, void* d_ws, size_t ws_size,
                              hipStream_t stream) {
    const float* t1 = (const float*)d_in[0];
    const float* t2 = (const float*)d_in[1];
    float* out      = (float*)d_out;
    corr_kernel<<<dim3(B_ * H_ / 2), NW * 64, 0, stream>>>(t1, t2, out);
}